// Round 9
// baseline (1000.672 us; speedup 1.0000x reference)
//
#include <hip/hip_runtime.h>

#define NB 64
#define NS 256
#define ND 2048
#define NH 16
#define NHD 128

typedef unsigned short ushort_t;
typedef __attribute__((ext_vector_type(8))) __bf16 bf16x8;
typedef __attribute__((ext_vector_type(4))) short shortx4;
typedef __attribute__((ext_vector_type(4))) float f32x4;
typedef __attribute__((ext_vector_type(4))) unsigned short ushortx4;

__device__ __forceinline__ unsigned short f2bf(float f) {
  union { float f; unsigned int u; } v; v.f = f;
  unsigned int r = v.u + 0x7FFFu + ((v.u >> 16) & 1u);
  return (unsigned short)(r >> 16);
}

__device__ __forceinline__ void gload16(const void* g, void* l) {
  __builtin_amdgcn_global_load_lds(
      (__attribute__((address_space(1))) void*)(void*)(g),
      (__attribute__((address_space(3))) void*)(l), 16, 0, 0);
}

__global__ void cast_f32_bf16(const float* __restrict__ in, ushort_t* __restrict__ out, long n) {
  long i = ((long)blockIdx.x * blockDim.x + threadIdx.x) * 4;
  if (i + 3 < n) {
    float4 v = *reinterpret_cast<const float4*>(in + i);
    ushortx4 o;
    o.x = f2bf(v.x); o.y = f2bf(v.y); o.z = f2bf(v.z); o.w = f2bf(v.w);
    *reinterpret_cast<ushortx4*>(out + i) = o;
  }
}

// ---------------------------------------------------------------------------
// 256x256 tile GEMM, BK=64, 8 waves (2M x 4N).
// Round-9 change: B OUT OF LDS. R8's cycle model: per tile MFMA=2484cy,
// LDS=2816cy (A+B reads + A+B stage) -> even perfect overlap is LDS-bound.
// B panel is L2-hot (<=1MB/block-col), so B frags now load global->reg per
// wave (8 x dwordx4/tile, vmem pipe) and LDS stages ONLY A (stage 32KB +
// 128 A-reads ~= 1792cy < MFMA 2484cy). Within-tile kk-split with counted
// lgkmcnt(8): kk1 A-reads (64/CU ~= 768cy) drain under kk0's MFMA (1033cy).
// vmcnt ledger (issue order pinned with sched_barrier(0), rule #18):
//   B(t)[8 oldest] -> A-stage(t+1)[4] -> ds_read kk0[8] -> kk1[8]
//   pre-MFMA: vmcnt(4) lgkmcnt(8)  (B landed; stage in flight)
//   mid:      lgkmcnt(0)           (kk1 ready, drained under kk0 MFMA)
//   end:      vmcnt(0) + barrier   (stage issued ~2500cy earlier -> free)
// T2 swizzle on A only (byte ^= (row&7)<<4; inverse on source, fwd on read).
// T1 bijective XCD swizzle.  MODE 0: fp32 C.  MODE 1: bf16 permuted qkv.
// ---------------------------------------------------------------------------
template<int MODE>
__global__ __launch_bounds__(512, 2) void gemm256(const ushort_t* __restrict__ A,
                                                  const ushort_t* __restrict__ Bt,
                                                  float* __restrict__ Cf,
                                                  ushort_t* __restrict__ Cq,
                                                  int M, int N, int K) {
  extern __shared__ char smem[];   // 2 bufs * 32768B (A only)
  const int tid = threadIdx.x;
  const int wv = tid >> 6, lane = tid & 63;
  const int l15 = lane & 15, lg = lane >> 4;
  const int wm = wv >> 2, wn = wv & 3;     // 2 x 4 wave grid; wave tile 128x64

  // T1: bijective XCD-aware block swizzle
  const int nbn = N >> 8;
  const int nwg = (M >> 8) * nbn;
  const int bid = blockIdx.x;
  const int q8 = nwg >> 3, r8 = nwg & 7;
  const int xcd = bid & 7, lin = bid >> 3;
  const int wg = (xcd < r8 ? xcd * (q8 + 1) : r8 * (q8 + 1) + (xcd - r8) * q8) + lin;
  const int m0 = (wg / nbn) << 8;
  const int n0 = (wg % nbn) << 8;

  // A staging (per-lane pre-swizzled source; LDS dest linear)
  const int srow = tid >> 3;                                  // 0..63
  const int sce = ((tid & 7) * 8) ^ ((srow & 7) << 3);        // elems
  const ushort_t* pa = A + (long)(m0 + srow) * K + sce;

  // ds_read byte-XOR: c(kk) = (kk*64 + lg*16) ^ ((l15&7)<<4)
  const int cx = (l15 & 7) << 4;
  const int c0 = (lg * 16) ^ cx;
  const int c1 = (64 + lg * 16) ^ cx;

  // B global->reg base: frag j covers row n0 + wn*64 + j*16 + l15, k-octet lg*8
  const ushort_t* pbase = Bt + (long)(n0 + wn * 64 + l15) * K + lg * 8;

  f32x4 acc[8][4] = {};
  const int nkt = K >> 6;          // K=2048 -> 32 tiles

  // prologue: stage A(0) -> buf0
  #pragma unroll
  for (int ch = 0; ch < 4; ++ch)
    gload16(pa + (long)(ch * 64) * K, smem + ch * 8192 + wv * 1024);
  asm volatile("s_waitcnt vmcnt(0)" ::: "memory");
  __builtin_amdgcn_s_barrier();

  for (int t = 0; t < nkt; ++t) {
    const char* rb = smem + (t & 1) * 32768;
    const long kof = (long)t * 64;
    // 1. B(t) global loads (oldest vmem this tile)
    bf16x8 b0[4], b1[4];
    #pragma unroll
    for (int j = 0; j < 4; ++j)
      b0[j] = *reinterpret_cast<const bf16x8*>(pbase + (long)(j * 16) * K + kof);
    #pragma unroll
    for (int j = 0; j < 4; ++j)
      b1[j] = *reinterpret_cast<const bf16x8*>(pbase + (long)(j * 16) * K + kof + 32);
    __builtin_amdgcn_sched_barrier(0);
    // 2. A-stage(t+1)
    if (t + 1 < nkt) {
      char* db = smem + ((t + 1) & 1) * 32768 + wv * 1024;
      #pragma unroll
      for (int ch = 0; ch < 4; ++ch)
        gload16(pa + (long)(ch * 64) * K + kof + 64, db + ch * 8192);
    }
    __builtin_amdgcn_sched_barrier(0);
    // 3. ds_read A: kk0 then kk1 (order matters for lgkmcnt(8))
    bf16x8 a0[8], a1[8];
    #pragma unroll
    for (int i = 0; i < 8; ++i)
      a0[i] = *reinterpret_cast<const bf16x8*>(rb + (wm * 128 + i * 16 + l15) * 128 + c0);
    #pragma unroll
    for (int i = 0; i < 8; ++i)
      a1[i] = *reinterpret_cast<const bf16x8*>(rb + (wm * 128 + i * 16 + l15) * 128 + c1);
    // 4. waits: kk0 LDS ready + B(t) landed (A-stage(t+1) stays in flight)
    if (t + 1 < nkt)
      asm volatile("s_waitcnt vmcnt(4) lgkmcnt(8)" ::: "memory");
    else
      asm volatile("s_waitcnt vmcnt(0) lgkmcnt(8)" ::: "memory");
    __builtin_amdgcn_sched_barrier(0);
    __builtin_amdgcn_s_setprio(1);
    #pragma unroll
    for (int i = 0; i < 8; ++i)
      #pragma unroll
      for (int j = 0; j < 4; ++j)
        acc[i][j] = __builtin_amdgcn_mfma_f32_16x16x32_bf16(a0[i], b0[j], acc[i][j], 0, 0, 0);
    __builtin_amdgcn_sched_barrier(0);
    asm volatile("s_waitcnt lgkmcnt(0)" ::: "memory");   // kk1 drained under kk0 MFMA
    __builtin_amdgcn_sched_barrier(0);
    #pragma unroll
    for (int i = 0; i < 8; ++i)
      #pragma unroll
      for (int j = 0; j < 4; ++j)
        acc[i][j] = __builtin_amdgcn_mfma_f32_16x16x32_bf16(a1[i], b1[j], acc[i][j], 0, 0, 0);
    __builtin_amdgcn_s_setprio(0);
    __builtin_amdgcn_sched_barrier(0);
    asm volatile("s_waitcnt vmcnt(0)" ::: "memory");  // A-stage(t+1) landed (free)
    __builtin_amdgcn_s_barrier();
  }

  // epilogue: D frag col = l15 (n), rows = lg*4 + r
  #pragma unroll
  for (int k = 0; k < 8; ++k) {
    const int mrow = m0 + wm * 128 + k * 16 + lg * 4;
    #pragma unroll
    for (int j = 0; j < 4; ++j) {
      const int n = n0 + wn * 64 + j * 16 + l15;
      #pragma unroll
      for (int r = 0; r < 4; ++r) {
        const int m = mrow + r;
        const float v = acc[k][j][r];
        if (MODE == 0) {
          Cf[(long)m * N + n] = v;
        } else {
          const int tq = n >> 11, hh = (n >> 7) & 15, hd = n & 127;
          const int b = m >> 8, s = m & 255;
          Cq[((((long)tq * NB + b) * NH + hh) * NS + s) * NHD + hd] = f2bf(v);
        }
      }
    }
  }
}

// One block per (b,h); 8 waves x 32 Q-rows. Flash-style online softmax.
// (R5 version — known-good.)
__global__ __launch_bounds__(512) void attn_fused(const ushort_t* __restrict__ qkv,
                                                  ushort_t* __restrict__ ctx) {
  const int bh = blockIdx.x;
  const int b = bh >> 4, h = bh & 15;
  const int wave = threadIdx.x >> 6, lane = threadIdx.x & 63;
  const int l15 = lane & 15, lg = lane >> 4;
  const long head_off = ((long)(b * NH + h)) * (NS * NHD);
  const ushort_t* Qp = qkv + head_off;
  const ushort_t* Kp = qkv + (long)NB * NH * NS * NHD + head_off;
  const ushort_t* Vp = qkv + 2L * NB * NH * NS * NHD + head_off;
  const int q0 = wave * 32;

  bf16x8 qf[2][4];
  #pragma unroll
  for (int ni = 0; ni < 2; ++ni)
    #pragma unroll
    for (int kk = 0; kk < 4; ++kk)
      qf[ni][kk] = *reinterpret_cast<const bf16x8*>(Qp + (q0 + ni * 16 + l15) * NHD + kk * 32 + lg * 8);

  f32x4 o[8][2] = {};
  float mstate[2] = {-1e30f, -1e30f};
  float lstate[2] = {0.f, 0.f};
  const float scale = 0.08838834764831845f;
  const int ntiles = (q0 + 32 + 63) >> 6;

  for (int kt = 0; kt < ntiles; ++kt) {
    f32x4 st[4][2] = {};
    #pragma unroll
    for (int kk = 0; kk < 4; ++kk) {
      bf16x8 kf[4];
      #pragma unroll
      for (int mi = 0; mi < 4; ++mi)
        kf[mi] = *reinterpret_cast<const bf16x8*>(Kp + (kt * 64 + mi * 16 + l15) * NHD + kk * 32 + lg * 8);
      #pragma unroll
      for (int mi = 0; mi < 4; ++mi)
        #pragma unroll
        for (int ni = 0; ni < 2; ++ni)
          st[mi][ni] = __builtin_amdgcn_mfma_f32_16x16x32_bf16(kf[mi], qf[ni][kk], st[mi][ni], 0, 0, 0);
    }
    const bool last = (kt == ntiles - 1);
    #pragma unroll
    for (int mi = 0; mi < 4; ++mi)
      #pragma unroll
      for (int ni = 0; ni < 2; ++ni)
        #pragma unroll
        for (int r = 0; r < 4; ++r) {
          const int kc = kt * 64 + mi * 16 + lg * 4 + r;
          const int q = q0 + ni * 16 + l15;
          float v = st[mi][ni][r] * scale;
          if (last && kc > q) v = -1e30f;
          st[mi][ni][r] = v;
        }
    shortx4 p[4][2];
    #pragma unroll
    for (int ni = 0; ni < 2; ++ni) {
      float tmax = -1e30f;
      #pragma unroll
      for (int mi = 0; mi < 4; ++mi)
        #pragma unroll
        for (int r = 0; r < 4; ++r) tmax = fmaxf(tmax, st[mi][ni][r]);
      tmax = fmaxf(tmax, __shfl_xor(tmax, 16, 64));
      tmax = fmaxf(tmax, __shfl_xor(tmax, 32, 64));
      const float mnew = fmaxf(mstate[ni], tmax);
      const float alpha = __expf(mstate[ni] - mnew);
      float tsum = 0.f;
      #pragma unroll
      for (int mi = 0; mi < 4; ++mi)
        #pragma unroll
        for (int r = 0; r < 4; ++r) {
          const float pe = __expf(st[mi][ni][r] - mnew);
          st[mi][ni][r] = pe;
          tsum += pe;
        }
      tsum += __shfl_xor(tsum, 16, 64);
      tsum += __shfl_xor(tsum, 32, 64);
      lstate[ni] = lstate[ni] * alpha + tsum;
      mstate[ni] = mnew;
      #pragma unroll
      for (int f = 0; f < 8; ++f)
        #pragma unroll
        for (int r = 0; r < 4; ++r) o[f][ni][r] *= alpha;
      #pragma unroll
      for (int mi = 0; mi < 4; ++mi)
        #pragma unroll
        for (int r = 0; r < 4; ++r) p[mi][ni][r] = (short)f2bf(st[mi][ni][r]);
    }
    #pragma unroll
    for (int f = 0; f < 8; ++f)
      #pragma unroll
      for (int mi = 0; mi < 4; ++mi) {
        shortx4 vt;
        #pragma unroll
        for (int j = 0; j < 4; ++j)
          vt[j] = (short)Vp[(kt * 64 + mi * 16 + lg * 4 + j) * NHD + f * 16 + l15];
        #pragma unroll
        for (int ni = 0; ni < 2; ++ni)
          o[f][ni] = __builtin_amdgcn_mfma_f32_16x16x16bf16_1k(vt, p[mi][ni], o[f][ni], 0, 0, 0);
      }
  }
  const float inv0 = 1.f / lstate[0], inv1 = 1.f / lstate[1];
  #pragma unroll
  for (int f = 0; f < 8; ++f)
    #pragma unroll
    for (int ni = 0; ni < 2; ++ni) {
      const float inv = ni ? inv1 : inv0;
      const int q = q0 + ni * 16 + l15;
      const int hd = f * 16 + lg * 4;
      ushortx4 ov;
      #pragma unroll
      for (int r = 0; r < 4; ++r) ov[r] = f2bf(o[f][ni][r] * inv);
      *reinterpret_cast<ushortx4*>(ctx + ((long)(b * NS + q)) * ND + h * NHD + hd) = ov;
    }
}

extern "C" void kernel_launch(void* const* d_in, const int* in_sizes, int n_in,
                              void* d_out, int out_size, void* d_ws, size_t ws_size,
                              hipStream_t stream) {
  const float* x     = (const float*)d_in[0];
  const float* w_qkv = (const float*)d_in[1];
  const float* w_o   = (const float*)d_in[2];
  char* ws = (char*)d_ws;
  if (ws_size < 369098752UL) return;
  ushort_t* xb    = (ushort_t*)(ws);
  ushort_t* wqkvb = (ushort_t*)(ws + 67108864L);
  ushort_t* wob   = (ushort_t*)(ws + 92274688L);
  ushort_t* qkvb  = (ushort_t*)(ws + 100663296L);
  ushort_t* ctxb  = (ushort_t*)(ws + 301989888L);

  const long nx = (long)NB * NS * ND;
  const long nq = 3L * ND * ND;
  const long no = (long)ND * ND;
  cast_f32_bf16<<<dim3(nx / 1024), 256, 0, stream>>>(x, xb, nx);
  cast_f32_bf16<<<dim3(nq / 1024), 256, 0, stream>>>(w_qkv, wqkvb, nq);
  cast_f32_bf16<<<dim3(no / 1024), 256, 0, stream>>>(w_o, wob, no);

  const int lds_bytes = 2 * 32768;  // 64 KiB (A-only double buffer, BK=64)
  (void)hipFuncSetAttribute(reinterpret_cast<const void*>(&gemm256<1>),
                            hipFuncAttributeMaxDynamicSharedMemorySize, lds_bytes);
  (void)hipFuncSetAttribute(reinterpret_cast<const void*>(&gemm256<0>),
                            hipFuncAttributeMaxDynamicSharedMemorySize, lds_bytes);

  // qkv = x @ w_qkv^T  -> permuted bf16 [3][B][H][S][HD]
  gemm256<1><<<dim3(64 * 24), 512, lds_bytes, stream>>>(xb, wqkvb, nullptr, qkvb,
                                                        NB * NS, 3 * ND, ND);
  // fused causal attention -> ctx bf16 [B][S][D]
  attn_fused<<<dim3(NB * NH), 512, 0, stream>>>(qkvb, ctxb);
  // out = ctx @ w_o^T  (fp32)
  gemm256<0><<<dim3(64 * 8), 512, lds_bytes, stream>>>(ctxb, wob, (float*)d_out, nullptr,
                                                       NB * NS, ND, ND);
}

// Round 10
// 698.488 us; speedup vs baseline: 1.4326x; 1.4326x over previous
//
#include <hip/hip_runtime.h>

#define NB 64
#define NS 256
#define ND 2048
#define NH 16
#define NHD 128

typedef unsigned short ushort_t;
typedef __attribute__((ext_vector_type(8))) __bf16 bf16x8;
typedef __attribute__((ext_vector_type(4))) short shortx4;
typedef __attribute__((ext_vector_type(4))) float f32x4;
typedef __attribute__((ext_vector_type(4))) unsigned short ushortx4;

__device__ __forceinline__ unsigned short f2bf(float f) {
  union { float f; unsigned int u; } v; v.f = f;
  unsigned int r = v.u + 0x7FFFu + ((v.u >> 16) & 1u);
  return (unsigned short)(r >> 16);
}

__device__ __forceinline__ void gload16(const void* g, void* l) {
  __builtin_amdgcn_global_load_lds(
      (__attribute__((address_space(1))) void*)(void*)(g),
      (__attribute__((address_space(3))) void*)(l), 16, 0, 0);
}

__global__ void cast_f32_bf16(const float* __restrict__ in, ushort_t* __restrict__ out, long n) {
  long i = ((long)blockIdx.x * blockDim.x + threadIdx.x) * 4;
  if (i + 3 < n) {
    float4 v = *reinterpret_cast<const float4*>(in + i);
    ushortx4 o;
    o.x = f2bf(v.x); o.y = f2bf(v.y); o.z = f2bf(v.z); o.w = f2bf(v.w);
    *reinterpret_cast<ushortx4*>(out + i) = o;
  }
}

// ---------------------------------------------------------------------------
// 256x256 tile GEMM, BK=64, 8 waves (2M x 4N), 2-buffer ring (A+B in LDS).
// Round-10 change (single variable vs R8): FINE PHASE GRANULARITY — the
// m201-verified quantum. Each K-tile = 4 phases; phase =
//   { ds_read subtile (<=12) ; stage 2 gload16 ; [lgkm(8) if 12 reads] ;
//     barrier ; lgkm(0) ; setprio(1) ; 16 MFMA (one quadrant) ; setprio(0) ;
//     barrier }
// Mechanism (m196/m233): 16-MFMA quanta let the 2 waves/SIMD alternate —
// one drains ds_reads while the other occupies the CU-shared MFMA pipe.
// R1-R8 monolithic clusters (all reads up front) measured fully serialized
// LDS<->MFMA (44-49% MfmaUtil).
// Quadrants: (iq,jq) over i=iq*4..+3, j=jq*2..+1, kk=0,1. A-half reads at
// ph0/ph2, B-half reads at ph0/ph1; stages: A01,A23,B01,B23.
// Waits stay conservative (R8-proven): lgkm(0) before every quantum,
// vmcnt(0)+barrier at tile end (stages issue 4 phases early -> free).
// T2 swizzle (byte ^= (row&7)<<4; inverse on source, fwd on read), T1
// bijective XCD swizzle. R9's B-from-global REVERTED (latency-bound, -68%).
// MODE 0: fp32 C.  MODE 1: bf16 permuted qkv [3][B][H][S][HD].
// ---------------------------------------------------------------------------
template<int MODE>
__global__ __launch_bounds__(512, 2) void gemm256(const ushort_t* __restrict__ A,
                                                  const ushort_t* __restrict__ Bt,
                                                  float* __restrict__ Cf,
                                                  ushort_t* __restrict__ Cq,
                                                  int M, int N, int K) {
  extern __shared__ char smem[];   // 2 bufs * 65536B; A at +0 (32KB), B at +32768
  const int tid = threadIdx.x;
  const int wv = tid >> 6, lane = tid & 63;
  const int l15 = lane & 15, lg = lane >> 4;
  const int wm = wv >> 2, wn = wv & 3;     // 2 x 4 wave grid; wave tile 128x64

  // T1: bijective XCD-aware block swizzle
  const int nbn = N >> 8;
  const int nwg = (M >> 8) * nbn;
  const int bid = blockIdx.x;
  const int q8 = nwg >> 3, r8 = nwg & 7;
  const int xcd = bid & 7, lin = bid >> 3;
  const int wg = (xcd < r8 ? xcd * (q8 + 1) : r8 * (q8 + 1) + (xcd - r8) * q8) + lin;
  const int m0 = (wg / nbn) << 8;
  const int n0 = (wg % nbn) << 8;

  // staging source (per-lane pre-swizzled; LDS dest linear)
  const int srow = tid >> 3;                                  // 0..63
  const int sce = ((tid & 7) * 8) ^ ((srow & 7) << 3);        // elems
  const ushort_t* pa = A  + (long)(m0 + srow) * K + sce;
  const ushort_t* pb = Bt + (long)(n0 + srow) * K + sce;

  // ds_read byte-XOR: c(kk) = (kk*64 + lg*16) ^ ((l15&7)<<4)
  const int cx = (l15 & 7) << 4;
  const int c0 = (lg * 16) ^ cx;
  const int c1 = (64 + lg * 16) ^ cx;

  f32x4 acc[8][4] = {};
  const int nkt = K >> 6;          // K=2048 -> 32 tiles

  // prologue: stage tile 0 -> buf0
  #pragma unroll
  for (int ch = 0; ch < 4; ++ch) {
    gload16(pa + (long)(ch * 64) * K, smem + ch * 8192 + wv * 1024);
    gload16(pb + (long)(ch * 64) * K, smem + 32768 + ch * 8192 + wv * 1024);
  }
  asm volatile("s_waitcnt vmcnt(0)" ::: "memory");
  __builtin_amdgcn_s_barrier();

  for (int t = 0; t < nkt; ++t) {
    const char* rb = smem + (t & 1) * 65536;
    char* db = smem + ((t + 1) & 1) * 65536 + wv * 1024;
    const long ko = (long)(t + 1) * 64;
    const bool pf = (t + 1 < nkt);
    bf16x8 a[4][2], b[4][2];
    const char* abase = rb + (wm * 128 + l15) * 128;
    const char* bbase = rb + 32768 + (wn * 64 + l15) * 128;

    // ================= phase 0: reads A-half0 (8) + B-half0 (4) ============
    #pragma unroll
    for (int i = 0; i < 4; ++i) {
      a[i][0] = *reinterpret_cast<const bf16x8*>(abase + i * 16 * 128 + c0);
      a[i][1] = *reinterpret_cast<const bf16x8*>(abase + i * 16 * 128 + c1);
    }
    #pragma unroll
    for (int j = 0; j < 2; ++j) {
      b[j][0] = *reinterpret_cast<const bf16x8*>(bbase + j * 16 * 128 + c0);
      b[j][1] = *reinterpret_cast<const bf16x8*>(bbase + j * 16 * 128 + c1);
    }
    if (pf) {
      gload16(pa + ko, db);
      gload16(pa + (long)64 * K + ko, db + 8192);
    }
    asm volatile("s_waitcnt lgkmcnt(8)" ::: "memory");
    __builtin_amdgcn_s_barrier();
    asm volatile("s_waitcnt lgkmcnt(0)" ::: "memory");
    __builtin_amdgcn_sched_barrier(0);
    __builtin_amdgcn_s_setprio(1);
    #pragma unroll
    for (int kk = 0; kk < 2; ++kk)
      #pragma unroll
      for (int i = 0; i < 4; ++i)
        #pragma unroll
        for (int j = 0; j < 2; ++j)
          acc[i][j] = __builtin_amdgcn_mfma_f32_16x16x32_bf16(a[i][kk], b[j][kk], acc[i][j], 0, 0, 0);
    __builtin_amdgcn_s_setprio(0);
    __builtin_amdgcn_s_barrier();

    // ================= phase 1: reads B-half1 (4) ==========================
    #pragma unroll
    for (int j = 2; j < 4; ++j) {
      b[j][0] = *reinterpret_cast<const bf16x8*>(bbase + j * 16 * 128 + c0);
      b[j][1] = *reinterpret_cast<const bf16x8*>(bbase + j * 16 * 128 + c1);
    }
    if (pf) {
      gload16(pa + (long)128 * K + ko, db + 16384);
      gload16(pa + (long)192 * K + ko, db + 24576);
    }
    __builtin_amdgcn_s_barrier();
    asm volatile("s_waitcnt lgkmcnt(0)" ::: "memory");
    __builtin_amdgcn_sched_barrier(0);
    __builtin_amdgcn_s_setprio(1);
    #pragma unroll
    for (int kk = 0; kk < 2; ++kk)
      #pragma unroll
      for (int i = 0; i < 4; ++i)
        #pragma unroll
        for (int j = 2; j < 4; ++j)
          acc[i][j] = __builtin_amdgcn_mfma_f32_16x16x32_bf16(a[i][kk], b[j][kk], acc[i][j], 0, 0, 0);
    __builtin_amdgcn_s_setprio(0);
    __builtin_amdgcn_s_barrier();

    // ================= phase 2: reads A-half1 (8, overwrite a) =============
    #pragma unroll
    for (int i = 0; i < 4; ++i) {
      a[i][0] = *reinterpret_cast<const bf16x8*>(abase + (64 + i * 16) * 128 + c0);
      a[i][1] = *reinterpret_cast<const bf16x8*>(abase + (64 + i * 16) * 128 + c1);
    }
    if (pf) {
      gload16(pb + ko, db + 32768);
      gload16(pb + (long)64 * K + ko, db + 32768 + 8192);
    }
    __builtin_amdgcn_s_barrier();
    asm volatile("s_waitcnt lgkmcnt(0)" ::: "memory");
    __builtin_amdgcn_sched_barrier(0);
    __builtin_amdgcn_s_setprio(1);
    #pragma unroll
    for (int kk = 0; kk < 2; ++kk)
      #pragma unroll
      for (int i = 0; i < 4; ++i)
        #pragma unroll
        for (int j = 0; j < 2; ++j)
          acc[4 + i][j] = __builtin_amdgcn_mfma_f32_16x16x32_bf16(a[i][kk], b[j][kk], acc[4 + i][j], 0, 0, 0);
    __builtin_amdgcn_s_setprio(0);
    __builtin_amdgcn_s_barrier();

    // ================= phase 3: no reads ===================================
    if (pf) {
      gload16(pb + (long)128 * K + ko, db + 32768 + 16384);
      gload16(pb + (long)192 * K + ko, db + 32768 + 24576);
    }
    __builtin_amdgcn_s_barrier();
    __builtin_amdgcn_sched_barrier(0);
    __builtin_amdgcn_s_setprio(1);
    #pragma unroll
    for (int kk = 0; kk < 2; ++kk)
      #pragma unroll
      for (int i = 0; i < 4; ++i)
        #pragma unroll
        for (int j = 2; j < 4; ++j)
          acc[4 + i][j] = __builtin_amdgcn_mfma_f32_16x16x32_bf16(a[i][kk], b[j][kk], acc[4 + i][j], 0, 0, 0);
    __builtin_amdgcn_s_setprio(0);
    __builtin_amdgcn_sched_barrier(0);
    asm volatile("s_waitcnt vmcnt(0)" ::: "memory");  // tile t+1 stage landed
    __builtin_amdgcn_s_barrier();
  }

  // epilogue: D frag col = l15 (n), rows = lg*4 + r
  #pragma unroll
  for (int k = 0; k < 8; ++k) {
    const int mrow = m0 + wm * 128 + k * 16 + lg * 4;
    #pragma unroll
    for (int j = 0; j < 4; ++j) {
      const int n = n0 + wn * 64 + j * 16 + l15;
      #pragma unroll
      for (int r = 0; r < 4; ++r) {
        const int m = mrow + r;
        const float v = acc[k][j][r];
        if (MODE == 0) {
          Cf[(long)m * N + n] = v;
        } else {
          const int tq = n >> 11, hh = (n >> 7) & 15, hd = n & 127;
          const int b = m >> 8, s = m & 255;
          Cq[((((long)tq * NB + b) * NH + hh) * NS + s) * NHD + hd] = f2bf(v);
        }
      }
    }
  }
}

// One block per (b,h); 8 waves x 32 Q-rows. Flash-style online softmax.
// (R5 version — known-good.)
__global__ __launch_bounds__(512) void attn_fused(const ushort_t* __restrict__ qkv,
                                                  ushort_t* __restrict__ ctx) {
  const int bh = blockIdx.x;
  const int b = bh >> 4, h = bh & 15;
  const int wave = threadIdx.x >> 6, lane = threadIdx.x & 63;
  const int l15 = lane & 15, lg = lane >> 4;
  const long head_off = ((long)(b * NH + h)) * (NS * NHD);
  const ushort_t* Qp = qkv + head_off;
  const ushort_t* Kp = qkv + (long)NB * NH * NS * NHD + head_off;
  const ushort_t* Vp = qkv + 2L * NB * NH * NS * NHD + head_off;
  const int q0 = wave * 32;

  bf16x8 qf[2][4];
  #pragma unroll
  for (int ni = 0; ni < 2; ++ni)
    #pragma unroll
    for (int kk = 0; kk < 4; ++kk)
      qf[ni][kk] = *reinterpret_cast<const bf16x8*>(Qp + (q0 + ni * 16 + l15) * NHD + kk * 32 + lg * 8);

  f32x4 o[8][2] = {};
  float mstate[2] = {-1e30f, -1e30f};
  float lstate[2] = {0.f, 0.f};
  const float scale = 0.08838834764831845f;
  const int ntiles = (q0 + 32 + 63) >> 6;

  for (int kt = 0; kt < ntiles; ++kt) {
    f32x4 st[4][2] = {};
    #pragma unroll
    for (int kk = 0; kk < 4; ++kk) {
      bf16x8 kf[4];
      #pragma unroll
      for (int mi = 0; mi < 4; ++mi)
        kf[mi] = *reinterpret_cast<const bf16x8*>(Kp + (kt * 64 + mi * 16 + l15) * NHD + kk * 32 + lg * 8);
      #pragma unroll
      for (int mi = 0; mi < 4; ++mi)
        #pragma unroll
        for (int ni = 0; ni < 2; ++ni)
          st[mi][ni] = __builtin_amdgcn_mfma_f32_16x16x32_bf16(kf[mi], qf[ni][kk], st[mi][ni], 0, 0, 0);
    }
    const bool last = (kt == ntiles - 1);
    #pragma unroll
    for (int mi = 0; mi < 4; ++mi)
      #pragma unroll
      for (int ni = 0; ni < 2; ++ni)
        #pragma unroll
        for (int r = 0; r < 4; ++r) {
          const int kc = kt * 64 + mi * 16 + lg * 4 + r;
          const int q = q0 + ni * 16 + l15;
          float v = st[mi][ni][r] * scale;
          if (last && kc > q) v = -1e30f;
          st[mi][ni][r] = v;
        }
    shortx4 p[4][2];
    #pragma unroll
    for (int ni = 0; ni < 2; ++ni) {
      float tmax = -1e30f;
      #pragma unroll
      for (int mi = 0; mi < 4; ++mi)
        #pragma unroll
        for (int r = 0; r < 4; ++r) tmax = fmaxf(tmax, st[mi][ni][r]);
      tmax = fmaxf(tmax, __shfl_xor(tmax, 16, 64));
      tmax = fmaxf(tmax, __shfl_xor(tmax, 32, 64));
      const float mnew = fmaxf(mstate[ni], tmax);
      const float alpha = __expf(mstate[ni] - mnew);
      float tsum = 0.f;
      #pragma unroll
      for (int mi = 0; mi < 4; ++mi)
        #pragma unroll
        for (int r = 0; r < 4; ++r) {
          const float pe = __expf(st[mi][ni][r] - mnew);
          st[mi][ni][r] = pe;
          tsum += pe;
        }
      tsum += __shfl_xor(tsum, 16, 64);
      tsum += __shfl_xor(tsum, 32, 64);
      lstate[ni] = lstate[ni] * alpha + tsum;
      mstate[ni] = mnew;
      #pragma unroll
      for (int f = 0; f < 8; ++f)
        #pragma unroll
        for (int r = 0; r < 4; ++r) o[f][ni][r] *= alpha;
      #pragma unroll
      for (int mi = 0; mi < 4; ++mi)
        #pragma unroll
        for (int r = 0; r < 4; ++r) p[mi][ni][r] = (short)f2bf(st[mi][ni][r]);
    }
    #pragma unroll
    for (int f = 0; f < 8; ++f)
      #pragma unroll
      for (int mi = 0; mi < 4; ++mi) {
        shortx4 vt;
        #pragma unroll
        for (int j = 0; j < 4; ++j)
          vt[j] = (short)Vp[(kt * 64 + mi * 16 + lg * 4 + j) * NHD + f * 16 + l15];
        #pragma unroll
        for (int ni = 0; ni < 2; ++ni)
          o[f][ni] = __builtin_amdgcn_mfma_f32_16x16x16bf16_1k(vt, p[mi][ni], o[f][ni], 0, 0, 0);
      }
  }
  const float inv0 = 1.f / lstate[0], inv1 = 1.f / lstate[1];
  #pragma unroll
  for (int f = 0; f < 8; ++f)
    #pragma unroll
    for (int ni = 0; ni < 2; ++ni) {
      const float inv = ni ? inv1 : inv0;
      const int q = q0 + ni * 16 + l15;
      const int hd = f * 16 + lg * 4;
      ushortx4 ov;
      #pragma unroll
      for (int r = 0; r < 4; ++r) ov[r] = f2bf(o[f][ni][r] * inv);
      *reinterpret_cast<ushortx4*>(ctx + ((long)(b * NS + q)) * ND + h * NHD + hd) = ov;
    }
}

extern "C" void kernel_launch(void* const* d_in, const int* in_sizes, int n_in,
                              void* d_out, int out_size, void* d_ws, size_t ws_size,
                              hipStream_t stream) {
  const float* x     = (const float*)d_in[0];
  const float* w_qkv = (const float*)d_in[1];
  const float* w_o   = (const float*)d_in[2];
  char* ws = (char*)d_ws;
  if (ws_size < 369098752UL) return;
  ushort_t* xb    = (ushort_t*)(ws);
  ushort_t* wqkvb = (ushort_t*)(ws + 67108864L);
  ushort_t* wob   = (ushort_t*)(ws + 92274688L);
  ushort_t* qkvb  = (ushort_t*)(ws + 100663296L);
  ushort_t* ctxb  = (ushort_t*)(ws + 301989888L);

  const long nx = (long)NB * NS * ND;
  const long nq = 3L * ND * ND;
  const long no = (long)ND * ND;
  cast_f32_bf16<<<dim3(nx / 1024), 256, 0, stream>>>(x, xb, nx);
  cast_f32_bf16<<<dim3(nq / 1024), 256, 0, stream>>>(w_qkv, wqkvb, nq);
  cast_f32_bf16<<<dim3(no / 1024), 256, 0, stream>>>(w_o, wob, no);

  const int lds_bytes = 2 * 65536;  // 128 KiB (2-buffer ring, A+B, BK=64)
  (void)hipFuncSetAttribute(reinterpret_cast<const void*>(&gemm256<1>),
                            hipFuncAttributeMaxDynamicSharedMemorySize, lds_bytes);
  (void)hipFuncSetAttribute(reinterpret_cast<const void*>(&gemm256<0>),
                            hipFuncAttributeMaxDynamicSharedMemorySize, lds_bytes);

  // qkv = x @ w_qkv^T  -> permuted bf16 [3][B][H][S][HD]
  gemm256<1><<<dim3(64 * 24), 512, lds_bytes, stream>>>(xb, wqkvb, nullptr, qkvb,
                                                        NB * NS, 3 * ND, ND);
  // fused causal attention -> ctx bf16 [B][S][D]
  attn_fused<<<dim3(NB * NH), 512, 0, stream>>>(qkvb, ctxb);
  // out = ctx @ w_o^T  (fp32)
  gemm256<0><<<dim3(64 * 8), 512, lds_bytes, stream>>>(ctxb, wob, (float*)d_out, nullptr,
                                                       NB * NS, ND, ND);
}

// Round 12
// 674.741 us; speedup vs baseline: 1.4830x; 1.0352x over previous
//
#include <hip/hip_runtime.h>

#define NB 64
#define NS 256
#define ND 2048
#define NH 16
#define NHD 128

typedef unsigned short ushort_t;
typedef __attribute__((ext_vector_type(8))) __bf16 bf16x8;
typedef __attribute__((ext_vector_type(4))) short shortx4;
typedef __attribute__((ext_vector_type(4))) float f32x4;
typedef __attribute__((ext_vector_type(4))) unsigned short ushortx4;

__device__ __forceinline__ unsigned short f2bf(float f) {
  union { float f; unsigned int u; } v; v.f = f;
  unsigned int r = v.u + 0x7FFFu + ((v.u >> 16) & 1u);
  return (unsigned short)(r >> 16);
}

__device__ __forceinline__ void gload16(const void* g, void* l) {
  __builtin_amdgcn_global_load_lds(
      (__attribute__((address_space(1))) void*)(void*)(g),
      (__attribute__((address_space(3))) void*)(l), 16, 0, 0);
}

__device__ __forceinline__ unsigned lds_off(const void* p) {
  return (unsigned)(size_t)(__attribute__((address_space(3))) const void*)p;
}

// ds_read_b64_tr_b16 (Model B, from m162's formula): each lane reads its OWN
// 64b at addr(l); delivery is a fixed cross-lane transpose within 16-lane
// groups: lane l elem j = element (l>>4)*64 + j*16 + (l&15) of the region at
// (group-uniform) base. Correct addressing: addr(l) = base + l*8.
template<int OFF>
__device__ __forceinline__ shortx4 tr16(unsigned addr) {
  shortx4 d;
  asm volatile("ds_read_b64_tr_b16 %0, %1 offset:%2"
               : "=v"(d) : "v"(addr), "i"(OFF));
  return d;
}

// Fused cast: one dispatch covers x (32768 blocks), w_qkv (12288), w_o (4096).
__global__ void cast3_f32_bf16(const float* __restrict__ x, const float* __restrict__ wq,
                               const float* __restrict__ wo, ushort_t* __restrict__ xb,
                               ushort_t* __restrict__ wqb, ushort_t* __restrict__ wob) {
  long bi = blockIdx.x;
  const float* src; ushort_t* dst;
  if (bi < 32768) { src = x; dst = xb; }
  else if (bi < 32768 + 12288) { bi -= 32768; src = wq; dst = wqb; }
  else { bi -= 32768 + 12288; src = wo; dst = wob; }
  const long i = (bi * 256 + threadIdx.x) * 4;
  float4 v = *reinterpret_cast<const float4*>(src + i);
  ushortx4 o;
  o.x = f2bf(v.x); o.y = f2bf(v.y); o.z = f2bf(v.z); o.w = f2bf(v.w);
  *reinterpret_cast<ushortx4*>(dst + i) = o;
}

// ---------------------------------------------------------------------------
// 256x256 tile GEMM, BK=64, 8 waves (2M x 4N), 2-buffer ring (R8 verbatim —
// best of 7 schedule variants: 387us GEMM1, MfmaUtil 48.9%, 1065 TF).
// ---------------------------------------------------------------------------
template<int MODE>
__global__ __launch_bounds__(512, 2) void gemm256(const ushort_t* __restrict__ A,
                                                  const ushort_t* __restrict__ Bt,
                                                  float* __restrict__ Cf,
                                                  ushort_t* __restrict__ Cq,
                                                  int M, int N, int K) {
  extern __shared__ char smem[];   // 2 bufs * 65536B; A at +0 (32KB), B at +32768
  const int tid = threadIdx.x;
  const int wv = tid >> 6, lane = tid & 63;
  const int l15 = lane & 15, lg = lane >> 4;
  const int wm = wv >> 2, wn = wv & 3;

  const int nbn = N >> 8;
  const int nwg = (M >> 8) * nbn;
  const int bid = blockIdx.x;
  const int q8 = nwg >> 3, r8 = nwg & 7;
  const int xcd = bid & 7, lin = bid >> 3;
  const int wg = (xcd < r8 ? xcd * (q8 + 1) : r8 * (q8 + 1) + (xcd - r8) * q8) + lin;
  const int m0 = (wg / nbn) << 8;
  const int n0 = (wg % nbn) << 8;

  const int srow = tid >> 3;
  const int sce = ((tid & 7) * 8) ^ ((srow & 7) << 3);
  const ushort_t* pa = A  + (long)(m0 + srow) * K + sce;
  const ushort_t* pb = Bt + (long)(n0 + srow) * K + sce;

  const int cx = (l15 & 7) << 4;
  const int c0 = (lg * 16) ^ cx;
  const int c1 = (64 + lg * 16) ^ cx;

  f32x4 acc[8][4] = {};
  const int nkt = K >> 6;

  #pragma unroll
  for (int ch = 0; ch < 4; ++ch) {
    gload16(pa + (long)(ch * 64) * K, smem + ch * 8192 + wv * 1024);
    gload16(pb + (long)(ch * 64) * K, smem + 32768 + ch * 8192 + wv * 1024);
  }
  asm volatile("s_waitcnt vmcnt(0)" ::: "memory");
  __builtin_amdgcn_s_barrier();

  for (int t = 0; t < nkt; ++t) {
    const char* rb = smem + (t & 1) * 65536;
    const long kof = (long)t * 64;
    if (t + 1 < nkt) {
      char* db = smem + ((t + 1) & 1) * 65536 + wv * 1024;
      #pragma unroll
      for (int ch = 0; ch < 4; ++ch) {
        gload16(pa + (long)(ch * 64) * K + kof + 64, db + ch * 8192);
        gload16(pb + (long)(ch * 64) * K + kof + 64, db + 32768 + ch * 8192);
      }
    }
    bf16x8 af[8][2], bf[4][2];
    #pragma unroll
    for (int i = 0; i < 8; ++i) {
      const char* base = rb + (wm * 128 + i * 16 + l15) * 128;
      af[i][0] = *reinterpret_cast<const bf16x8*>(base + c0);
      af[i][1] = *reinterpret_cast<const bf16x8*>(base + c1);
    }
    #pragma unroll
    for (int j = 0; j < 4; ++j) {
      const char* base = rb + 32768 + (wn * 64 + j * 16 + l15) * 128;
      bf[j][0] = *reinterpret_cast<const bf16x8*>(base + c0);
      bf[j][1] = *reinterpret_cast<const bf16x8*>(base + c1);
    }
    asm volatile("s_waitcnt lgkmcnt(0)" ::: "memory");
    __builtin_amdgcn_sched_barrier(0);
    __builtin_amdgcn_s_setprio(1);
    #pragma unroll
    for (int kk = 0; kk < 2; ++kk)
      #pragma unroll
      for (int i = 0; i < 8; ++i)
        #pragma unroll
        for (int j = 0; j < 4; ++j)
          acc[i][j] = __builtin_amdgcn_mfma_f32_16x16x32_bf16(af[i][kk], bf[j][kk], acc[i][j], 0, 0, 0);
    __builtin_amdgcn_s_setprio(0);
    __builtin_amdgcn_sched_barrier(0);
    asm volatile("s_waitcnt vmcnt(0)" ::: "memory");
    __builtin_amdgcn_s_barrier();
  }

  #pragma unroll
  for (int k = 0; k < 8; ++k) {
    const int mrow = m0 + wm * 128 + k * 16 + lg * 4;
    #pragma unroll
    for (int j = 0; j < 4; ++j) {
      const int n = n0 + wn * 64 + j * 16 + l15;
      #pragma unroll
      for (int r = 0; r < 4; ++r) {
        const int m = mrow + r;
        const float v = acc[k][j][r];
        if (MODE == 0) {
          Cf[(long)m * N + n] = v;
        } else {
          const int tq = n >> 11, hh = (n >> 7) & 15, hd = n & 127;
          const int b = m >> 8, s = m & 255;
          Cq[((((long)tq * NB + b) * NH + hh) * NS + s) * NHD + hd] = f2bf(v);
        }
      }
    }
  }
}

// ---------------------------------------------------------------------------
// Fused causal attention. One block per (b,h); 8 waves x 32 Q-rows.
// V staged block-cooperatively into LDS, subtiled [hd/16][kv/4][4][16],
// consumed via ds_read_b64_tr_b16 (Model B: addr = base + lane*8; offset
// walks subtiles f*2048 + mi*512). Round-12 fix: R11 used the Model-A addr
// (lg*128 + l15*2) -> wrong elements under the true cross-lane-transpose
// semantics -> absmax 5.5. Staging map verified: dest e = call*4096 + tid*8
// + c holds V[kv=((tid>>3)&15)*4 + ((tid>>1)&3)][hd=call*64+(tid>>7)*16+
// (tid&1)*8+c], matching the layout decomposition.
// ---------------------------------------------------------------------------
__global__ __launch_bounds__(512, 2) void attn_fused(const ushort_t* __restrict__ qkv,
                                                     ushort_t* __restrict__ ctx) {
  __shared__ char vsm[32768];                 // 2 bufs x 16KB
  const int bh = blockIdx.x;
  const int b = bh >> 4, h = bh & 15;
  const int tid = threadIdx.x;
  const int wave = tid >> 6, lane = tid & 63;
  const int l15 = lane & 15, lg = lane >> 4;
  const long head_off = ((long)(b * NH + h)) * (NS * NHD);
  const ushort_t* Qp = qkv + head_off;
  const ushort_t* Kp = qkv + (long)NB * NH * NS * NHD + head_off;
  const ushort_t* Vp = qkv + 2L * NB * NH * NS * NHD + head_off;
  const int q0 = wave * 32;
  const int klast = (q0 + 31) >> 6;           // 0,0,1,1,2,2,3,3

  // V staging source map (dest elem e = call*4096 + tid*8 + c):
  const int t7 = tid & 127;
  const int srowv = ((t7 >> 3) << 2) | ((t7 >> 1) & 3);        // kv row 0..63
  const int vcol = (tid >> 7) * 16 + (t7 & 1) * 8;             // hd (call adds 64)
  const ushort_t* vsrc = Vp + srowv * NHD + vcol;

  bf16x8 qf[2][4];
  #pragma unroll
  for (int ni = 0; ni < 2; ++ni)
    #pragma unroll
    for (int kk = 0; kk < 4; ++kk)
      qf[ni][kk] = *reinterpret_cast<const bf16x8*>(Qp + (q0 + ni * 16 + l15) * NHD + kk * 32 + lg * 8);

  f32x4 o[8][2] = {};
  float mstate[2] = {-1e30f, -1e30f};
  float lstate[2] = {0.f, 0.f};
  const float scale = 0.08838834764831845f;

  // prologue: stage V(0) -> buf0
  gload16(vsrc, vsm + wave * 1024);
  gload16(vsrc + 64, vsm + 8192 + wave * 1024);
  asm volatile("s_waitcnt vmcnt(0)" ::: "memory");
  __builtin_amdgcn_s_barrier();

  for (int kt = 0; kt < 4; ++kt) {
    // stage V(kt+1) -> buf^1 (all waves; latency hides under QK+softmax)
    if (kt + 1 < 4) {
      char* db = vsm + ((kt + 1) & 1) * 16384 + wave * 1024;
      const ushort_t* s = vsrc + (kt + 1) * 64 * NHD;
      gload16(s, db);
      gload16(s + 64, db + 8192);
    }
    shortx4 p[4][2];
    const bool act = (kt <= klast);
    if (act) {
      f32x4 st[4][2] = {};
      #pragma unroll
      for (int kk = 0; kk < 4; ++kk) {
        bf16x8 kf[4];
        #pragma unroll
        for (int mi = 0; mi < 4; ++mi)
          kf[mi] = *reinterpret_cast<const bf16x8*>(Kp + (kt * 64 + mi * 16 + l15) * NHD + kk * 32 + lg * 8);
        #pragma unroll
        for (int mi = 0; mi < 4; ++mi)
          #pragma unroll
          for (int ni = 0; ni < 2; ++ni)
            st[mi][ni] = __builtin_amdgcn_mfma_f32_16x16x32_bf16(kf[mi], qf[ni][kk], st[mi][ni], 0, 0, 0);
      }
      const bool dom = (kt == klast);
      #pragma unroll
      for (int mi = 0; mi < 4; ++mi)
        #pragma unroll
        for (int ni = 0; ni < 2; ++ni)
          #pragma unroll
          for (int r = 0; r < 4; ++r) {
            const int kc = kt * 64 + mi * 16 + lg * 4 + r;
            const int q = q0 + ni * 16 + l15;
            float v = st[mi][ni][r] * scale;
            if (dom && kc > q) v = -1e30f;
            st[mi][ni][r] = v;
          }
      #pragma unroll
      for (int ni = 0; ni < 2; ++ni) {
        float tmax = -1e30f;
        #pragma unroll
        for (int mi = 0; mi < 4; ++mi)
          #pragma unroll
          for (int r = 0; r < 4; ++r) tmax = fmaxf(tmax, st[mi][ni][r]);
        tmax = fmaxf(tmax, __shfl_xor(tmax, 16, 64));
        tmax = fmaxf(tmax, __shfl_xor(tmax, 32, 64));
        const float mnew = fmaxf(mstate[ni], tmax);
        const float alpha = __expf(mstate[ni] - mnew);
        float tsum = 0.f;
        #pragma unroll
        for (int mi = 0; mi < 4; ++mi)
          #pragma unroll
          for (int r = 0; r < 4; ++r) {
            const float pe = __expf(st[mi][ni][r] - mnew);
            st[mi][ni][r] = pe;
            tsum += pe;
          }
        tsum += __shfl_xor(tsum, 16, 64);
        tsum += __shfl_xor(tsum, 32, 64);
        lstate[ni] = lstate[ni] * alpha + tsum;
        mstate[ni] = mnew;
        #pragma unroll
        for (int f = 0; f < 8; ++f)
          #pragma unroll
          for (int r = 0; r < 4; ++r) o[f][ni][r] *= alpha;
        #pragma unroll
        for (int mi = 0; mi < 4; ++mi)
          #pragma unroll
          for (int r = 0; r < 4; ++r) p[mi][ni][r] = (short)f2bf(st[mi][ni][r]);
      }
      // PV via hardware transpose-read of staged V (Model B addressing)
      const unsigned va = lds_off(vsm) + (unsigned)((kt & 1) * 16384 + lane * 8);
#define PVF(F)                                                                  \
      {                                                                         \
        shortx4 v0 = tr16<(F)*2048 +    0>(va);                                 \
        shortx4 v1 = tr16<(F)*2048 +  512>(va);                                 \
        shortx4 v2 = tr16<(F)*2048 + 1024>(va);                                 \
        shortx4 v3 = tr16<(F)*2048 + 1536>(va);                                 \
        asm volatile("s_waitcnt lgkmcnt(0)" ::: "memory");                      \
        __builtin_amdgcn_sched_barrier(0);                                      \
        o[F][0] = __builtin_amdgcn_mfma_f32_16x16x16bf16_1k(v0, p[0][0], o[F][0], 0, 0, 0); \
        o[F][1] = __builtin_amdgcn_mfma_f32_16x16x16bf16_1k(v0, p[0][1], o[F][1], 0, 0, 0); \
        o[F][0] = __builtin_amdgcn_mfma_f32_16x16x16bf16_1k(v1, p[1][0], o[F][0], 0, 0, 0); \
        o[F][1] = __builtin_amdgcn_mfma_f32_16x16x16bf16_1k(v1, p[1][1], o[F][1], 0, 0, 0); \
        o[F][0] = __builtin_amdgcn_mfma_f32_16x16x16bf16_1k(v2, p[2][0], o[F][0], 0, 0, 0); \
        o[F][1] = __builtin_amdgcn_mfma_f32_16x16x16bf16_1k(v2, p[2][1], o[F][1], 0, 0, 0); \
        o[F][0] = __builtin_amdgcn_mfma_f32_16x16x16bf16_1k(v3, p[3][0], o[F][0], 0, 0, 0); \
        o[F][1] = __builtin_amdgcn_mfma_f32_16x16x16bf16_1k(v3, p[3][1], o[F][1], 0, 0, 0); \
      }
      PVF(0) PVF(1) PVF(2) PVF(3) PVF(4) PVF(5) PVF(6) PVF(7)
#undef PVF
    }
    // drain stage(kt+1); all waves done with buf[kt&1]
    asm volatile("s_waitcnt vmcnt(0)" ::: "memory");
    __builtin_amdgcn_s_barrier();
  }

  const float inv0 = 1.f / lstate[0], inv1 = 1.f / lstate[1];
  #pragma unroll
  for (int f = 0; f < 8; ++f)
    #pragma unroll
    for (int ni = 0; ni < 2; ++ni) {
      const float inv = ni ? inv1 : inv0;
      const int q = q0 + ni * 16 + l15;
      const int hd = f * 16 + lg * 4;
      ushortx4 ov;
      #pragma unroll
      for (int r = 0; r < 4; ++r) ov[r] = f2bf(o[f][ni][r] * inv);
      *reinterpret_cast<ushortx4*>(ctx + ((long)(b * NS + q)) * ND + h * NHD + hd) = ov;
    }
}

extern "C" void kernel_launch(void* const* d_in, const int* in_sizes, int n_in,
                              void* d_out, int out_size, void* d_ws, size_t ws_size,
                              hipStream_t stream) {
  const float* x     = (const float*)d_in[0];
  const float* w_qkv = (const float*)d_in[1];
  const float* w_o   = (const float*)d_in[2];
  char* ws = (char*)d_ws;
  if (ws_size < 369098752UL) return;
  ushort_t* xb    = (ushort_t*)(ws);
  ushort_t* wqkvb = (ushort_t*)(ws + 67108864L);
  ushort_t* wob   = (ushort_t*)(ws + 92274688L);
  ushort_t* qkvb  = (ushort_t*)(ws + 100663296L);
  ushort_t* ctxb  = (ushort_t*)(ws + 301989888L);

  // fused cast: x (32768 blocks) + w_qkv (12288) + w_o (4096)
  cast3_f32_bf16<<<dim3(49152), 256, 0, stream>>>(x, w_qkv, w_o, xb, wqkvb, wob);

  const int lds_bytes = 2 * 65536;  // 128 KiB (2-buffer ring, A+B, BK=64)
  (void)hipFuncSetAttribute(reinterpret_cast<const void*>(&gemm256<1>),
                            hipFuncAttributeMaxDynamicSharedMemorySize, lds_bytes);
  (void)hipFuncSetAttribute(reinterpret_cast<const void*>(&gemm256<0>),
                            hipFuncAttributeMaxDynamicSharedMemorySize, lds_bytes);

  // qkv = x @ w_qkv^T  -> permuted bf16 [3][B][H][S][HD]
  gemm256<1><<<dim3(64 * 24), 512, lds_bytes, stream>>>(xb, wqkvb, nullptr, qkvb,
                                                        NB * NS, 3 * ND, ND);
  // fused causal attention -> ctx bf16 [B][S][D]
  attn_fused<<<dim3(NB * NH), 512, 0, stream>>>(qkvb, ctxb);
  // out = ctx @ w_o^T  (fp32)
  gemm256<0><<<dim3(64 * 8), 512, lds_bytes, stream>>>(ctxb, wob, (float*)d_out, nullptr,
                                                       NB * NS, ND, ND);
}